// Round 1
// baseline (677.411 us; speedup 1.0000x reference)
//
#include <hip/hip_runtime.h>

#define S_LEN 2048
#define DM    1024
#define NHEAD 16
#define HDIM  64
#define NB    2
#define NROWS (NB * S_LEN)   // 4096

using f32x4  = __attribute__((ext_vector_type(4))) float;
using bf16x8 = __attribute__((ext_vector_type(8))) __bf16;

__device__ __forceinline__ ushort f2bf(float f) {
  unsigned u = __builtin_bit_cast(unsigned, f);
  u += 0x7fffu + ((u >> 16) & 1u);
  return (ushort)(u >> 16);
}
__device__ __forceinline__ float bf2f(ushort h) {
  unsigned u = ((unsigned)h) << 16;
  return __builtin_bit_cast(float, u);
}
__device__ __forceinline__ f32x4 mfma16(bf16x8 a, bf16x8 b, f32x4 c) {
  return __builtin_amdgcn_mfma_f32_16x16x32_bf16(a, b, c, 0, 0, 0);
}

// ---------------- split fp32 -> bf16 hi + bf16 lo ----------------
__global__ void split_kernel(const float* __restrict__ in, ushort* __restrict__ hi,
                             ushort* __restrict__ lo, int n4) {
  int i = blockIdx.x * 256 + threadIdx.x;
  if (i >= n4) return;
  float4 v = ((const float4*)in)[i];
  float vals[4] = {v.x, v.y, v.z, v.w};
  ushort h[4], l[4];
#pragma unroll
  for (int j = 0; j < 4; ++j) {
    h[j] = f2bf(vals[j]);
    l[j] = f2bf(vals[j] - bf2f(h[j]));
  }
  ((ushort4*)hi)[i] = make_ushort4(h[0], h[1], h[2], h[3]);
  ((ushort4*)lo)[i] = make_ushort4(l[0], l[1], l[2], l[3]);
}

// ---------------- split-bf16 NT GEMM: C = (Ah+Al)[M,K] * ((Bh+Bl)[N,K])^T ----
// 128x128 tile, BK=64, 256 threads = 4 waves (2x2), each wave 64x64 out.
// EPI 0: QKV epilogue (N=3072): cols [0,1024) -> Q hi/lo [B,H,S,64],
//        [1024,2048) -> K hi/lo, [2048,3072) -> V bf16 [B,H,S,64]. Adds biases.
// EPI 1: fp32 out[M,Ncols] = acc + biasQ[j].
template<int EPI>
__global__ __launch_bounds__(256, 1)
void gemm_split(const ushort* __restrict__ Ah, const ushort* __restrict__ Al,
                const ushort* __restrict__ Bh, const ushort* __restrict__ Bl,
                const float* __restrict__ biasQ, const float* __restrict__ biasK,
                const float* __restrict__ biasV,
                float* __restrict__ outF,
                ushort* __restrict__ Qh, ushort* __restrict__ Ql,
                ushort* __restrict__ Kh, ushort* __restrict__ Kl,
                ushort* __restrict__ Vb, int Ncols)
{
  constexpr int K = 1024;
  __shared__ ushort sAh[128][72];
  __shared__ ushort sAl[128][72];
  __shared__ ushort sBh[128][72];
  __shared__ ushort sBl[128][72];
  const int t = threadIdx.x;
  const int w = t >> 6, l = t & 63;
  const int lr = l >> 4, lc = l & 15;
  const int wr = w >> 1, wc = w & 1;
  const int i0 = blockIdx.y * 128, j0 = blockIdx.x * 128;

  f32x4 acc[4][4] = {};
  const int cr = t >> 3;          // staging: thread covers rows cr, cr+32, cr+64, cr+96
  const int cc = (t & 7) * 8;     // 8 bf16 = 16B chunk

  for (int k0 = 0; k0 < K; k0 += 64) {
#pragma unroll
    for (int jj = 0; jj < 4; ++jj) {
      int r = jj * 32 + cr;
      size_t ga = (size_t)(i0 + r) * K + (k0 + cc);
      size_t gb = (size_t)(j0 + r) * K + (k0 + cc);
      *(uint4*)&sAh[r][cc] = *(const uint4*)(Ah + ga);
      *(uint4*)&sAl[r][cc] = *(const uint4*)(Al + ga);
      *(uint4*)&sBh[r][cc] = *(const uint4*)(Bh + gb);
      *(uint4*)&sBl[r][cc] = *(const uint4*)(Bl + gb);
    }
    __syncthreads();
#pragma unroll
    for (int kk = 0; kk < 2; ++kk) {
      bf16x8 ah[4], al[4], bh[4], bl[4];
#pragma unroll
      for (int m = 0; m < 4; ++m) {
        ah[m] = *(const bf16x8*)&sAh[wr*64 + m*16 + lc][kk*32 + lr*8];
        al[m] = *(const bf16x8*)&sAl[wr*64 + m*16 + lc][kk*32 + lr*8];
      }
#pragma unroll
      for (int n = 0; n < 4; ++n) {
        bh[n] = *(const bf16x8*)&sBh[wc*64 + n*16 + lc][kk*32 + lr*8];
        bl[n] = *(const bf16x8*)&sBl[wc*64 + n*16 + lc][kk*32 + lr*8];
      }
#pragma unroll
      for (int m = 0; m < 4; ++m)
#pragma unroll
        for (int n = 0; n < 4; ++n) {
          acc[m][n] = mfma16(ah[m], bh[n], acc[m][n]);
          acc[m][n] = mfma16(ah[m], bl[n], acc[m][n]);
          acc[m][n] = mfma16(al[m], bh[n], acc[m][n]);
        }
    }
    __syncthreads();
  }

#pragma unroll
  for (int m = 0; m < 4; ++m)
#pragma unroll
    for (int n = 0; n < 4; ++n)
#pragma unroll
      for (int r = 0; r < 4; ++r) {
        int i = i0 + wr*64 + m*16 + lr*4 + r;
        int j = j0 + wc*64 + n*16 + lc;
        float v = acc[m][n][r];
        if constexpr (EPI == 0) {
          int region = j >> 10;
          int jc = j & 1023;
          int h = jc >> 6, d = jc & 63;
          int b = i >> 11, s = i & 2047;
          size_t idx = ((size_t)(b * NHEAD + h) * S_LEN + s) * HDIM + d;
          if (region == 0) {
            v += biasQ[jc];
            ushort hv = f2bf(v);
            Qh[idx] = hv; Ql[idx] = f2bf(v - bf2f(hv));
          } else if (region == 1) {
            v += biasK[jc];
            ushort hv = f2bf(v);
            Kh[idx] = hv; Kl[idx] = f2bf(v - bf2f(hv));
          } else {
            v += biasV[jc];
            Vb[idx] = f2bf(v);
          }
        } else {
          v += biasQ[j];
          outF[(size_t)i * Ncols + j] = v;
        }
      }
}

// ---------------- V [B,H,S,64] -> Vt [B,H,64,S] ----------------
__global__ void transpose_v(const ushort* __restrict__ V, ushort* __restrict__ Vt) {
  __shared__ ushort tile[64][72];
  const int st = blockIdx.x, bh = blockIdx.y;
  const int t = threadIdx.x;
#pragma unroll
  for (int jj = 0; jj < 2; ++jj) {
    int c = jj * 256 + t;
    int rr = c >> 3, cc = (c & 7) * 8;
    *(uint4*)&tile[rr][cc] =
        *(const uint4*)&V[(((size_t)bh * S_LEN) + st*64 + rr) * HDIM + cc];
  }
  __syncthreads();
#pragma unroll
  for (int jj = 0; jj < 2; ++jj) {
    int c = jj * 256 + t;
    int d = c >> 3, s8 = (c & 7) * 8;
    alignas(16) ushort vals[8];
#pragma unroll
    for (int u = 0; u < 8; ++u) vals[u] = tile[s8 + u][d];
    *(uint4*)&Vt[(((size_t)bh * HDIM) + d) * S_LEN + st*64 + s8] = *(uint4*)vals;
  }
}

// ---------------- flash attention (causal, no 1/sqrt(d) scale) ----------------
// grid: (qt=S/64, bh=B*H). block 256 = 4 waves; wave w owns q rows qt*64+w*16..+15.
__global__ __launch_bounds__(256, 2)
void attn_kernel(const ushort* __restrict__ Qh, const ushort* __restrict__ Ql,
                 const ushort* __restrict__ Kh, const ushort* __restrict__ Kl,
                 const ushort* __restrict__ Vt,
                 ushort* __restrict__ Oh, ushort* __restrict__ Ol)
{
  __shared__ ushort Plds[4][16][72];
  const int qt = blockIdx.x, bh = blockIdx.y;
  const int t = threadIdx.x, w = t >> 6, l = t & 63;
  const int lr = l >> 4, lc = l & 15;
  const size_t base = (size_t)bh * S_LEN * HDIM;
  const int q0 = qt * 64 + w * 16;

  // Q fragments hoisted (rows q0+lc, k-dims ks*32 + lr*8 .. +7)
  bf16x8 aQh[2], aQl[2];
#pragma unroll
  for (int ks = 0; ks < 2; ++ks) {
    size_t qa = base + (size_t)(q0 + lc) * HDIM + ks*32 + lr*8;
    aQh[ks] = *(const bf16x8*)(Qh + qa);
    aQl[ks] = *(const bf16x8*)(Ql + qa);
  }
  f32x4 oacc[4] = {};
  float mrow[4] = {-3e38f, -3e38f, -3e38f, -3e38f};
  float lsum[4] = {0.f, 0.f, 0.f, 0.f};

  for (int kt = 0; kt <= qt; ++kt) {
    f32x4 sacc[4] = {};
#pragma unroll
    for (int n = 0; n < 4; ++n) {
#pragma unroll
      for (int ks = 0; ks < 2; ++ks) {
        size_t ka = base + (size_t)(kt*64 + n*16 + lc) * HDIM + ks*32 + lr*8;
        bf16x8 kh = *(const bf16x8*)(Kh + ka);
        bf16x8 kl = *(const bf16x8*)(Kl + ka);
        sacc[n] = mfma16(aQh[ks], kh, sacc[n]);
        sacc[n] = mfma16(aQl[ks], kh, sacc[n]);
        sacc[n] = mfma16(aQh[ks], kl, sacc[n]);
      }
    }
    if (kt == qt) {   // causal mask on the diagonal tile
#pragma unroll
      for (int n = 0; n < 4; ++n)
#pragma unroll
        for (int r = 0; r < 4; ++r) {
          int kg = kt*64 + n*16 + lc;
          int qg = q0 + lr*4 + r;
          if (kg > qg) sacc[n][r] = -1e30f;
        }
    }
    float mnew[4], scale[4], rsum[4];
#pragma unroll
    for (int r = 0; r < 4; ++r) {
      float rm = fmaxf(fmaxf(sacc[0][r], sacc[1][r]), fmaxf(sacc[2][r], sacc[3][r]));
      rm = fmaxf(rm, __shfl_xor(rm, 1));
      rm = fmaxf(rm, __shfl_xor(rm, 2));
      rm = fmaxf(rm, __shfl_xor(rm, 4));
      rm = fmaxf(rm, __shfl_xor(rm, 8));
      mnew[r] = fmaxf(mrow[r], rm);
      scale[r] = __expf(mrow[r] - mnew[r]);
      mrow[r] = mnew[r];
      rsum[r] = 0.f;
    }
#pragma unroll
    for (int n = 0; n < 4; ++n)
#pragma unroll
      for (int r = 0; r < 4; ++r) {
        float p = __expf(sacc[n][r] - mnew[r]);
        sacc[n][r] = p;
        rsum[r] += p;
      }
#pragma unroll
    for (int r = 0; r < 4; ++r) {
      float rs = rsum[r];
      rs += __shfl_xor(rs, 1);
      rs += __shfl_xor(rs, 2);
      rs += __shfl_xor(rs, 4);
      rs += __shfl_xor(rs, 8);
      lsum[r] = lsum[r] * scale[r] + rs;
    }
    // P (C-layout) -> LDS, re-read as A-fragments (per-wave private region)
#pragma unroll
    for (int n = 0; n < 4; ++n)
#pragma unroll
      for (int r = 0; r < 4; ++r)
        Plds[w][lr*4 + r][n*16 + lc] = f2bf(sacc[n][r]);
#pragma unroll
    for (int dt = 0; dt < 4; ++dt)
#pragma unroll
      for (int r = 0; r < 4; ++r)
        oacc[dt][r] *= scale[r];
#pragma unroll
    for (int ks = 0; ks < 2; ++ks) {
      bf16x8 ap = *(const bf16x8*)&Plds[w][lc][ks*32 + lr*8];
#pragma unroll
      for (int dt = 0; dt < 4; ++dt) {
        size_t va = ((size_t)bh * HDIM + dt*16 + lc) * S_LEN + kt*64 + ks*32 + lr*8;
        bf16x8 bv = *(const bf16x8*)(Vt + va);
        oacc[dt] = mfma16(ap, bv, oacc[dt]);
      }
    }
  }
  const int b = bh >> 4, h = bh & 15;
#pragma unroll
  for (int dt = 0; dt < 4; ++dt)
#pragma unroll
    for (int r = 0; r < 4; ++r) {
      int qg = q0 + lr*4 + r;
      float o = oacc[dt][r] / lsum[r];
      size_t row = (size_t)b * S_LEN + qg;
      int col = h * HDIM + dt*16 + lc;
      ushort hv = f2bf(o);
      Oh[row * DM + col] = hv;
      Ol[row * DM + col] = f2bf(o - bf2f(hv));
    }
}

extern "C" void kernel_launch(void* const* d_in, const int* in_sizes, int n_in,
                              void* d_out, int out_size, void* d_ws, size_t ws_size,
                              hipStream_t stream)
{
  const float* x  = (const float*)d_in[0];
  // d_in[1] = mask: exactly tril by construction; causality applied analytically.
  const float* Wq = (const float*)d_in[2];
  const float* bq = (const float*)d_in[3];
  const float* Wk = (const float*)d_in[4];
  const float* bk = (const float*)d_in[5];
  const float* Wv = (const float*)d_in[6];
  const float* bv = (const float*)d_in[7];
  const float* Wo = (const float*)d_in[8];
  const float* bo = (const float*)d_in[9];
  float* out = (float*)d_out;

  char* ws = (char*)d_ws;
  size_t off = 0;
  auto alloc = [&](size_t bytes) { char* p = ws + off; off += bytes; return p; };
  const size_t XN = (size_t)NROWS * DM;   // 4,194,304 elements
  const size_t WN = (size_t)DM * DM;      // 1,048,576

  ushort* Xh  = (ushort*)alloc(XN * 2);
  ushort* Xl  = (ushort*)alloc(XN * 2);
  ushort* Wh  = (ushort*)alloc(3 * WN * 2);   // packed Wq|Wk|Wv
  ushort* Wl  = (ushort*)alloc(3 * WN * 2);
  ushort* Woh = (ushort*)alloc(WN * 2);
  ushort* Wol = (ushort*)alloc(WN * 2);
  ushort* Qh  = (ushort*)alloc(XN * 2);
  ushort* Ql  = (ushort*)alloc(XN * 2);
  ushort* Kh  = (ushort*)alloc(XN * 2);
  ushort* Kl  = (ushort*)alloc(XN * 2);
  ushort* Vb  = (ushort*)alloc(XN * 2);
  ushort* Vt  = (ushort*)alloc(XN * 2);
  ushort* Oh  = (ushort*)alloc(XN * 2);
  ushort* Ol  = (ushort*)alloc(XN * 2);
  (void)ws_size; (void)in_sizes; (void)n_in; (void)out_size;

  split_kernel<<<(int)(XN/4/256), 256, 0, stream>>>(x,  Xh, Xl, (int)(XN/4));
  split_kernel<<<(int)(WN/4/256), 256, 0, stream>>>(Wq, Wh,          Wl,          (int)(WN/4));
  split_kernel<<<(int)(WN/4/256), 256, 0, stream>>>(Wk, Wh + WN,     Wl + WN,     (int)(WN/4));
  split_kernel<<<(int)(WN/4/256), 256, 0, stream>>>(Wv, Wh + 2*WN,   Wl + 2*WN,   (int)(WN/4));
  split_kernel<<<(int)(WN/4/256), 256, 0, stream>>>(Wo, Woh, Wol, (int)(WN/4));

  gemm_split<0><<<dim3(24, 32), 256, 0, stream>>>(Xh, Xl, Wh, Wl, bq, bk, bv,
                                                  nullptr, Qh, Ql, Kh, Kl, Vb, 3072);
  transpose_v<<<dim3(32, 32), 256, 0, stream>>>(Vb, Vt);
  attn_kernel<<<dim3(32, 32), 256, 0, stream>>>(Qh, Ql, Kh, Kl, Vt, Oh, Ol);
  gemm_split<1><<<dim3(8, 32), 256, 0, stream>>>(Oh, Ol, Woh, Wol, bo, nullptr, nullptr,
                                                 out, nullptr, nullptr, nullptr,
                                                 nullptr, nullptr, 1024);
}

// Round 2
// 346.425 us; speedup vs baseline: 1.9554x; 1.9554x over previous
//
#include <hip/hip_runtime.h>

#define S_LEN 2048
#define DM    1024
#define NHEAD 16
#define HDIM  64
#define NB    2
#define NROWS (NB * S_LEN)   // 4096

using f32x4  = __attribute__((ext_vector_type(4))) float;
using bf16x8 = __attribute__((ext_vector_type(8))) __bf16;

__device__ __forceinline__ ushort f2bf(float f) {
  unsigned u = __builtin_bit_cast(unsigned, f);
  u += 0x7fffu + ((u >> 16) & 1u);
  return (ushort)(u >> 16);
}
__device__ __forceinline__ float bf2f(ushort h) {
  unsigned u = ((unsigned)h) << 16;
  return __builtin_bit_cast(float, u);
}
__device__ __forceinline__ unsigned pack_bf16(float lo, float hi) {
  return (unsigned)f2bf(lo) | ((unsigned)f2bf(hi) << 16);
}
__device__ __forceinline__ f32x4 mfma16(bf16x8 a, bf16x8 b, f32x4 c) {
  return __builtin_amdgcn_mfma_f32_16x16x32_bf16(a, b, c, 0, 0, 0);
}

// ---------------- split fp32 -> bf16 hi + bf16 lo ----------------
__global__ void split_kernel(const float* __restrict__ in, ushort* __restrict__ hi,
                             ushort* __restrict__ lo, int n4) {
  int i = blockIdx.x * 256 + threadIdx.x;
  if (i >= n4) return;
  float4 v = ((const float4*)in)[i];
  float vals[4] = {v.x, v.y, v.z, v.w};
  ushort h[4], l[4];
#pragma unroll
  for (int j = 0; j < 4; ++j) {
    h[j] = f2bf(vals[j]);
    l[j] = f2bf(vals[j] - bf2f(h[j]));
  }
  ((ushort4*)hi)[i] = make_ushort4(h[0], h[1], h[2], h[3]);
  ((ushort4*)lo)[i] = make_ushort4(l[0], l[1], l[2], l[3]);
}

// ---------------- split-bf16 NT GEMM: C = (Ah+Al)[M,K] * ((Bh+Bl)[N,K])^T ----
template<int EPI>
__global__ __launch_bounds__(256, 2)
void gemm_split(const ushort* __restrict__ Ah, const ushort* __restrict__ Al,
                const ushort* __restrict__ Bh, const ushort* __restrict__ Bl,
                const float* __restrict__ biasQ, const float* __restrict__ biasK,
                const float* __restrict__ biasV,
                float* __restrict__ outF,
                ushort* __restrict__ Qh, ushort* __restrict__ Ql,
                ushort* __restrict__ Kh, ushort* __restrict__ Kl,
                ushort* __restrict__ Vb, int Ncols)
{
  constexpr int K = 1024;
  __shared__ ushort sAh[128][72];
  __shared__ ushort sAl[128][72];
  __shared__ ushort sBh[128][72];
  __shared__ ushort sBl[128][72];
  const int t = threadIdx.x;
  const int w = t >> 6, l = t & 63;
  const int lr = l >> 4, lc = l & 15;
  const int wr = w >> 1, wc = w & 1;
  // XCD-chunked bijective swizzle (nwg % 8 == 0 for both grids)
  const int nwg = gridDim.x * gridDim.y;
  const int lin = blockIdx.y * gridDim.x + blockIdx.x;
  const int per8 = nwg >> 3;
  const int swz = (lin & 7) * per8 + (lin >> 3);
  const int i0 = (swz / gridDim.x) * 128, j0 = (swz % gridDim.x) * 128;

  f32x4 acc[4][4] = {};
  const int cr = t >> 3;
  const int cc = (t & 7) * 8;

  for (int k0 = 0; k0 < K; k0 += 64) {
#pragma unroll
    for (int jj = 0; jj < 4; ++jj) {
      int r = jj * 32 + cr;
      size_t ga = (size_t)(i0 + r) * K + (k0 + cc);
      size_t gb = (size_t)(j0 + r) * K + (k0 + cc);
      *(uint4*)&sAh[r][cc] = *(const uint4*)(Ah + ga);
      *(uint4*)&sAl[r][cc] = *(const uint4*)(Al + ga);
      *(uint4*)&sBh[r][cc] = *(const uint4*)(Bh + gb);
      *(uint4*)&sBl[r][cc] = *(const uint4*)(Bl + gb);
    }
    __syncthreads();
#pragma unroll
    for (int kk = 0; kk < 2; ++kk) {
      bf16x8 ah[4], al[4], bh[4], bl[4];
#pragma unroll
      for (int m = 0; m < 4; ++m) {
        ah[m] = *(const bf16x8*)&sAh[wr*64 + m*16 + lc][kk*32 + lr*8];
        al[m] = *(const bf16x8*)&sAl[wr*64 + m*16 + lc][kk*32 + lr*8];
      }
#pragma unroll
      for (int n = 0; n < 4; ++n) {
        bh[n] = *(const bf16x8*)&sBh[wc*64 + n*16 + lc][kk*32 + lr*8];
        bl[n] = *(const bf16x8*)&sBl[wc*64 + n*16 + lc][kk*32 + lr*8];
      }
#pragma unroll
      for (int m = 0; m < 4; ++m)
#pragma unroll
        for (int n = 0; n < 4; ++n) {
          acc[m][n] = mfma16(ah[m], bh[n], acc[m][n]);
          acc[m][n] = mfma16(ah[m], bl[n], acc[m][n]);
          acc[m][n] = mfma16(al[m], bh[n], acc[m][n]);
        }
    }
    __syncthreads();
  }

#pragma unroll
  for (int m = 0; m < 4; ++m)
#pragma unroll
    for (int n = 0; n < 4; ++n)
#pragma unroll
      for (int r = 0; r < 4; ++r) {
        int i = i0 + wr*64 + m*16 + lr*4 + r;
        int j = j0 + wc*64 + n*16 + lc;
        float v = acc[m][n][r];
        if constexpr (EPI == 0) {
          int region = j >> 10;
          int jc = j & 1023;
          int h = jc >> 6, d = jc & 63;
          int b = i >> 11, s = i & 2047;
          size_t idx = ((size_t)(b * NHEAD + h) * S_LEN + s) * HDIM + d;
          if (region == 0) {
            v += biasQ[jc];
            ushort hv = f2bf(v);
            Qh[idx] = hv; Ql[idx] = f2bf(v - bf2f(hv));
          } else if (region == 1) {
            v += biasK[jc];
            ushort hv = f2bf(v);
            Kh[idx] = hv; Kl[idx] = f2bf(v - bf2f(hv));
          } else {
            v += biasV[jc];
            Vb[idx] = f2bf(v);
          }
        } else {
          v += biasQ[j];
          outF[(size_t)i * Ncols + j] = v;
        }
      }
}

// ---------------- V [B,H,S,64] -> Vt [B,H,64,S] ----------------
__global__ void transpose_v(const ushort* __restrict__ V, ushort* __restrict__ Vt) {
  __shared__ ushort tile[64][72];
  const int st = blockIdx.x, bh = blockIdx.y;
  const int t = threadIdx.x;
#pragma unroll
  for (int jj = 0; jj < 2; ++jj) {
    int c = jj * 256 + t;
    int rr = c >> 3, cc = (c & 7) * 8;
    *(uint4*)&tile[rr][cc] =
        *(const uint4*)&V[(((size_t)bh * S_LEN) + st*64 + rr) * HDIM + cc];
  }
  __syncthreads();
#pragma unroll
  for (int jj = 0; jj < 2; ++jj) {
    int c = jj * 256 + t;
    int d = c >> 3, s8 = (c & 7) * 8;
    alignas(16) ushort vals[8];
#pragma unroll
    for (int u = 0; u < 8; ++u) vals[u] = tile[s8 + u][d];
    *(uint4*)&Vt[(((size_t)bh * HDIM) + d) * S_LEN + st*64 + s8] = *(uint4*)vals;
  }
}

// ---------------- flash attention, swapped-QK layout ----------------
// grid (32,32). Per-CU-balanced (qt,bh) permutation: each CU's 4 resident
// blocks get qt = {v, 31-v, (v+8)&31, 31-((v+8)&31)} -> uniform 66 kt-iters.
// Swapped QK^T: s = mfma(K, Q) -> C[row=k][col=q]; each lane owns one q-column
// with 16 k-values in registers -> in-lane softmax reduce + 2 shuffles.
__global__ __launch_bounds__(256, 4)
void attn_kernel(const ushort* __restrict__ Qh, const ushort* __restrict__ Ql,
                 const ushort* __restrict__ Kh, const ushort* __restrict__ Kl,
                 const ushort* __restrict__ Vt,
                 ushort* __restrict__ Oh, ushort* __restrict__ Ol)
{
  __shared__ ushort Plds[4][16][72];
  const int lin = blockIdx.y * gridDim.x + blockIdx.x;
  const int s4 = lin >> 8, pp = lin & 255, v = pp & 31, b8 = pp >> 5;
  int qt;
  if      (s4 == 0) qt = v;
  else if (s4 == 1) qt = 31 - v;
  else if (s4 == 2) qt = (v + 8) & 31;
  else              qt = 31 - ((v + 8) & 31);
  const int bh = b8 * 4 + s4;

  const int t = threadIdx.x, w = t >> 6, l = t & 63;
  const int g = l >> 4, q = l & 15;   // g: 16-lane group, q: lane-within-16
  const size_t base = (size_t)bh * S_LEN * HDIM;
  const int q0 = qt * 64 + w * 16;

  // Q as B-fragments: B[kdim][col=q] -> Q[q0+q][ks*32 + g*8 + j]
  bf16x8 bQh[2], bQl[2];
#pragma unroll
  for (int ks = 0; ks < 2; ++ks) {
    size_t qa = base + (size_t)(q0 + q) * HDIM + ks*32 + g*8;
    bQh[ks] = *(const bf16x8*)(Qh + qa);
    bQl[ks] = *(const bf16x8*)(Ql + qa);
  }

  f32x4 oacc[4] = {};
  float m = -3e38f, lsum = 0.f;

  for (int kt = 0; kt <= qt; ++kt) {
    // S^T tile: rows = k (in regs), cols = q (lanes)
    f32x4 s[4] = {};
#pragma unroll
    for (int n = 0; n < 4; ++n) {
#pragma unroll
      for (int ks = 0; ks < 2; ++ks) {
        size_t ka = base + (size_t)(kt*64 + n*16 + q) * HDIM + ks*32 + g*8;
        bf16x8 kh = *(const bf16x8*)(Kh + ka);
        bf16x8 kl = *(const bf16x8*)(Kl + ka);
        s[n] = mfma16(kh, bQh[ks], s[n]);
        s[n] = mfma16(kl, bQh[ks], s[n]);
        s[n] = mfma16(kh, bQl[ks], s[n]);
      }
    }
    if (kt == qt) {  // causal mask on diagonal tile: lane holds k = n*16+g*4+r
      const int qg = q0 + q;
#pragma unroll
      for (int n = 0; n < 4; ++n)
#pragma unroll
        for (int r = 0; r < 4; ++r) {
          int kg = kt*64 + n*16 + g*4 + r;
          if (kg > qg) s[n][r] = -1e30f;
        }
    }
    // column max: 16 in-lane values + reduce across g (xor16, xor32)
    float pm = -3e38f;
#pragma unroll
    for (int n = 0; n < 4; ++n)
#pragma unroll
      for (int r = 0; r < 4; ++r) pm = fmaxf(pm, s[n][r]);
    pm = fmaxf(pm, __shfl_xor(pm, 16));
    pm = fmaxf(pm, __shfl_xor(pm, 32));
    float mnew = fmaxf(m, pm);
    float sc = __expf(m - mnew);
    m = mnew;
    float rs = 0.f;
#pragma unroll
    for (int n = 0; n < 4; ++n)
#pragma unroll
      for (int r = 0; r < 4; ++r) {
        float pe = __expf(s[n][r] - mnew);
        s[n][r] = pe;
        rs += pe;
      }
    rs += __shfl_xor(rs, 16);
    rs += __shfl_xor(rs, 32);
    lsum = lsum * sc + rs;

    // P^T -> LDS: Plds[w][q][k], lane owns k = n*16+g*4+{0..3}, packed pairs
#pragma unroll
    for (int n = 0; n < 4; ++n) {
      *(unsigned*)&Plds[w][q][n*16 + g*4]     = pack_bf16(s[n][0], s[n][1]);
      *(unsigned*)&Plds[w][q][n*16 + g*4 + 2] = pack_bf16(s[n][2], s[n][3]);
    }
    // broadcast per-output-row scale: row (g*4+r) owner is lane (g*4+r)
    float scr[4];
#pragma unroll
    for (int r = 0; r < 4; ++r) scr[r] = __shfl(sc, g*4 + r);
#pragma unroll
    for (int dt = 0; dt < 4; ++dt)
#pragma unroll
      for (int r = 0; r < 4; ++r) oacc[dt][r] *= scr[r];

    // PV: A = P (row=q, k contiguous from LDS), B = Vt
#pragma unroll
    for (int ks = 0; ks < 2; ++ks) {
      bf16x8 ap = *(const bf16x8*)&Plds[w][q][ks*32 + g*8];
#pragma unroll
      for (int dt = 0; dt < 4; ++dt) {
        size_t va = ((size_t)bh * HDIM + dt*16 + q) * S_LEN + kt*64 + ks*32 + g*8;
        bf16x8 bv = *(const bf16x8*)(Vt + va);
        oacc[dt] = mfma16(ap, bv, oacc[dt]);
      }
    }
  }

  float lsr[4];
#pragma unroll
  for (int r = 0; r < 4; ++r) lsr[r] = __shfl(lsum, g*4 + r);
  const int b = bh >> 4, h = bh & 15;
#pragma unroll
  for (int dt = 0; dt < 4; ++dt)
#pragma unroll
    for (int r = 0; r < 4; ++r) {
      int qg = q0 + g*4 + r;
      float o = oacc[dt][r] / lsr[r];
      size_t row = (size_t)b * S_LEN + qg;
      int col = h * HDIM + dt*16 + q;
      ushort hv = f2bf(o);
      Oh[row * DM + col] = hv;
      Ol[row * DM + col] = f2bf(o - bf2f(hv));
    }
}

extern "C" void kernel_launch(void* const* d_in, const int* in_sizes, int n_in,
                              void* d_out, int out_size, void* d_ws, size_t ws_size,
                              hipStream_t stream)
{
  const float* x  = (const float*)d_in[0];
  const float* Wq = (const float*)d_in[2];
  const float* bq = (const float*)d_in[3];
  const float* Wk = (const float*)d_in[4];
  const float* bk = (const float*)d_in[5];
  const float* Wv = (const float*)d_in[6];
  const float* bv = (const float*)d_in[7];
  const float* Wo = (const float*)d_in[8];
  const float* bo = (const float*)d_in[9];
  float* out = (float*)d_out;

  char* ws = (char*)d_ws;
  size_t off = 0;
  auto alloc = [&](size_t bytes) { char* p = ws + off; off += bytes; return p; };
  const size_t XN = (size_t)NROWS * DM;
  const size_t WN = (size_t)DM * DM;

  ushort* Xh  = (ushort*)alloc(XN * 2);
  ushort* Xl  = (ushort*)alloc(XN * 2);
  ushort* Wh  = (ushort*)alloc(3 * WN * 2);
  ushort* Wl  = (ushort*)alloc(3 * WN * 2);
  ushort* Woh = (ushort*)alloc(WN * 2);
  ushort* Wol = (ushort*)alloc(WN * 2);
  ushort* Qh  = (ushort*)alloc(XN * 2);
  ushort* Ql  = (ushort*)alloc(XN * 2);
  ushort* Kh  = (ushort*)alloc(XN * 2);
  ushort* Kl  = (ushort*)alloc(XN * 2);
  ushort* Vb  = (ushort*)alloc(XN * 2);
  ushort* Vt  = (ushort*)alloc(XN * 2);
  ushort* Oh  = (ushort*)alloc(XN * 2);
  ushort* Ol  = (ushort*)alloc(XN * 2);
  (void)ws_size; (void)in_sizes; (void)n_in; (void)out_size;

  split_kernel<<<(int)(XN/4/256), 256, 0, stream>>>(x,  Xh, Xl, (int)(XN/4));
  split_kernel<<<(int)(WN/4/256), 256, 0, stream>>>(Wq, Wh,        Wl,        (int)(WN/4));
  split_kernel<<<(int)(WN/4/256), 256, 0, stream>>>(Wk, Wh + WN,   Wl + WN,   (int)(WN/4));
  split_kernel<<<(int)(WN/4/256), 256, 0, stream>>>(Wv, Wh + 2*WN, Wl + 2*WN, (int)(WN/4));
  split_kernel<<<(int)(WN/4/256), 256, 0, stream>>>(Wo, Woh, Wol, (int)(WN/4));

  gemm_split<0><<<dim3(24, 32), 256, 0, stream>>>(Xh, Xl, Wh, Wl, bq, bk, bv,
                                                  nullptr, Qh, Ql, Kh, Kl, Vb, 3072);
  transpose_v<<<dim3(32, 32), 256, 0, stream>>>(Vb, Vt);
  attn_kernel<<<dim3(32, 32), 256, 0, stream>>>(Qh, Ql, Kh, Kl, Vt, Oh, Ol);
  gemm_split<1><<<dim3(8, 32), 256, 0, stream>>>(Oh, Ol, Woh, Wol, bo, nullptr, nullptr,
                                                 out, nullptr, nullptr, nullptr,
                                                 nullptr, nullptr, 1024);
}

// Round 3
// 224.102 us; speedup vs baseline: 3.0228x; 1.5458x over previous
//
#include <hip/hip_runtime.h>

#define S_LEN 2048
#define DM    1024
#define NHEAD 16
#define HDIM  64
#define NB    2
#define NROWS (NB * S_LEN)   // 4096

using f32x4  = __attribute__((ext_vector_type(4))) float;
using bf16x8 = __attribute__((ext_vector_type(8))) __bf16;

__device__ __forceinline__ ushort f2bf(float f) {
  unsigned u = __builtin_bit_cast(unsigned, f);
  u += 0x7fffu + ((u >> 16) & 1u);
  return (ushort)(u >> 16);
}
__device__ __forceinline__ float bf2f(ushort h) {
  unsigned u = ((unsigned)h) << 16;
  return __builtin_bit_cast(float, u);
}
__device__ __forceinline__ unsigned pack_bf16(float lo, float hi) {
  return (unsigned)f2bf(lo) | ((unsigned)f2bf(hi) << 16);
}
__device__ __forceinline__ f32x4 mfma16(bf16x8 a, bf16x8 b, f32x4 c) {
  return __builtin_amdgcn_mfma_f32_16x16x32_bf16(a, b, c, 0, 0, 0);
}
__device__ __forceinline__ void async16(const ushort* g, ushort* l) {
  __builtin_amdgcn_global_load_lds(
      (const __attribute__((address_space(1))) unsigned*)g,
      (__attribute__((address_space(3))) unsigned*)l, 16, 0, 0);
}

// ---------------- split fp32 -> bf16 hi + bf16 lo ----------------
__global__ void split_kernel(const float* __restrict__ in, ushort* __restrict__ hi,
                             ushort* __restrict__ lo, int n4) {
  int i = blockIdx.x * 256 + threadIdx.x;
  if (i >= n4) return;
  float4 v = ((const float4*)in)[i];
  float vals[4] = {v.x, v.y, v.z, v.w};
  ushort h[4], l[4];
#pragma unroll
  for (int j = 0; j < 4; ++j) {
    h[j] = f2bf(vals[j]);
    l[j] = f2bf(vals[j] - bf2f(h[j]));
  }
  ((ushort4*)hi)[i] = make_ushort4(h[0], h[1], h[2], h[3]);
  ((ushort4*)lo)[i] = make_ushort4(l[0], l[1], l[2], l[3]);
}

// ---------------- split-bf16 NT GEMM: C = (Ah+Al)[M,K] * ((Bh+Bl)[N,K])^T ----
template<int EPI>
__global__ __launch_bounds__(256, 2)
void gemm_split(const ushort* __restrict__ Ah, const ushort* __restrict__ Al,
                const ushort* __restrict__ Bh, const ushort* __restrict__ Bl,
                const float* __restrict__ biasQ, const float* __restrict__ biasK,
                const float* __restrict__ biasV,
                float* __restrict__ outF,
                ushort* __restrict__ Qh, ushort* __restrict__ Ql,
                ushort* __restrict__ Kh, ushort* __restrict__ Kl,
                ushort* __restrict__ Vb, int Ncols)
{
  constexpr int K = 1024;
  __shared__ ushort sAh[128][72];
  __shared__ ushort sAl[128][72];
  __shared__ ushort sBh[128][72];
  __shared__ ushort sBl[128][72];
  const int t = threadIdx.x;
  const int w = t >> 6, l = t & 63;
  const int lr = l >> 4, lc = l & 15;
  const int wr = w >> 1, wc = w & 1;
  const int nwg = gridDim.x * gridDim.y;
  const int lin = blockIdx.y * gridDim.x + blockIdx.x;
  const int per8 = nwg >> 3;
  const int swz = (lin & 7) * per8 + (lin >> 3);
  const int i0 = (swz / gridDim.x) * 128, j0 = (swz % gridDim.x) * 128;

  f32x4 acc[4][4] = {};
  const int cr = t >> 3;
  const int cc = (t & 7) * 8;

  for (int k0 = 0; k0 < K; k0 += 64) {
#pragma unroll
    for (int jj = 0; jj < 4; ++jj) {
      int r = jj * 32 + cr;
      size_t ga = (size_t)(i0 + r) * K + (k0 + cc);
      size_t gb = (size_t)(j0 + r) * K + (k0 + cc);
      *(uint4*)&sAh[r][cc] = *(const uint4*)(Ah + ga);
      *(uint4*)&sAl[r][cc] = *(const uint4*)(Al + ga);
      *(uint4*)&sBh[r][cc] = *(const uint4*)(Bh + gb);
      *(uint4*)&sBl[r][cc] = *(const uint4*)(Bl + gb);
    }
    __syncthreads();
#pragma unroll
    for (int kk = 0; kk < 2; ++kk) {
      bf16x8 ah[4], al[4], bh[4], bl[4];
#pragma unroll
      for (int m = 0; m < 4; ++m) {
        ah[m] = *(const bf16x8*)&sAh[wr*64 + m*16 + lc][kk*32 + lr*8];
        al[m] = *(const bf16x8*)&sAl[wr*64 + m*16 + lc][kk*32 + lr*8];
      }
#pragma unroll
      for (int n = 0; n < 4; ++n) {
        bh[n] = *(const bf16x8*)&sBh[wc*64 + n*16 + lc][kk*32 + lr*8];
        bl[n] = *(const bf16x8*)&sBl[wc*64 + n*16 + lc][kk*32 + lr*8];
      }
#pragma unroll
      for (int m = 0; m < 4; ++m)
#pragma unroll
        for (int n = 0; n < 4; ++n) {
          acc[m][n] = mfma16(ah[m], bh[n], acc[m][n]);
          acc[m][n] = mfma16(ah[m], bl[n], acc[m][n]);
          acc[m][n] = mfma16(al[m], bh[n], acc[m][n]);
        }
    }
    __syncthreads();
  }

#pragma unroll
  for (int m = 0; m < 4; ++m)
#pragma unroll
    for (int n = 0; n < 4; ++n)
#pragma unroll
      for (int r = 0; r < 4; ++r) {
        int i = i0 + wr*64 + m*16 + lr*4 + r;
        int j = j0 + wc*64 + n*16 + lc;
        float v = acc[m][n][r];
        if constexpr (EPI == 0) {
          int region = j >> 10;
          int jc = j & 1023;
          int h = jc >> 6, d = jc & 63;
          int b = i >> 11, s = i & 2047;
          size_t idx = ((size_t)(b * NHEAD + h) * S_LEN + s) * HDIM + d;
          if (region == 0) {
            v += biasQ[jc];
            ushort hv = f2bf(v);
            Qh[idx] = hv; Ql[idx] = f2bf(v - bf2f(hv));
          } else if (region == 1) {
            v += biasK[jc];
            ushort hv = f2bf(v);
            Kh[idx] = hv; Kl[idx] = f2bf(v - bf2f(hv));
          } else {
            v += biasV[jc];
            Vb[idx] = f2bf(v);
          }
        } else {
          v += biasQ[j];
          outF[(size_t)i * Ncols + j] = v;
        }
      }
}

// ---------------- V [B,H,S,64] -> Vt [B,H,64,S] ----------------
__global__ void transpose_v(const ushort* __restrict__ V, ushort* __restrict__ Vt) {
  __shared__ ushort tile[64][72];
  const int st = blockIdx.x, bh = blockIdx.y;
  const int t = threadIdx.x;
#pragma unroll
  for (int jj = 0; jj < 2; ++jj) {
    int c = jj * 256 + t;
    int rr = c >> 3, cc = (c & 7) * 8;
    *(uint4*)&tile[rr][cc] =
        *(const uint4*)&V[(((size_t)bh * S_LEN) + st*64 + rr) * HDIM + cc];
  }
  __syncthreads();
#pragma unroll
  for (int jj = 0; jj < 2; ++jj) {
    int c = jj * 256 + t;
    int d = c >> 3, s8 = (c & 7) * 8;
    alignas(16) ushort vals[8];
#pragma unroll
    for (int u = 0; u < 8; ++u) vals[u] = tile[s8 + u][d];
    *(uint4*)&Vt[(((size_t)bh * HDIM) + d) * S_LEN + st*64 + s8] = *(uint4*)vals;
  }
}

// ---------------- flash attention: LDS-staged K/V, oversubscribed grid ------
// 2048 blocks x 128 thr (2 waves). Job lin: v = 63-(lin>>5) (longest first),
// bh = lin&31 (same-bh jobs land on the same XCD under round-robin dispatch).
// Per kt: stage Kh/Kl/V 64x64 tiles into LDS via global_load_lds(16B), with
// T2 XOR-swizzle (byte ^= (row&7)<<4) applied by pre-swizzling the global
// source column (linear LDS dest, rule #21). 2-phase: stage -> vmcnt(0)+bar
// -> compute -> bar. Swapped QK^T keeps softmax in-register (2 shuffles).
__global__ __launch_bounds__(128, 3)
void attn_kernel(const ushort* __restrict__ Qh, const ushort* __restrict__ Ql,
                 const ushort* __restrict__ Kh, const ushort* __restrict__ Kl,
                 const ushort* __restrict__ Vt,
                 ushort* __restrict__ Oh, ushort* __restrict__ Ol)
{
  __shared__ ushort sKV[3 * 64 * 64];   // [Kh | Kl | V], rows XOR-swizzled
  __shared__ ushort Plds[2][16][72];
  const int lin = blockIdx.x;
  const int v  = 63 - (lin >> 5);
  const int bh = lin & 31;
  const int t = threadIdx.x, w = t >> 6, l = t & 63;
  const int g = l >> 4, q = l & 15;
  const size_t base = (size_t)bh * S_LEN * HDIM;
  const int q0 = v * 32 + w * 16;
  const int nkt = (v >> 1) + 1;

  // Q as B-fragments (rows q0+q)
  bf16x8 bQh[2], bQl[2];
#pragma unroll
  for (int ks = 0; ks < 2; ++ks) {
    size_t qa = base + (size_t)(q0 + q) * HDIM + ks*32 + g*8;
    bQh[ks] = *(const bf16x8*)(Qh + qa);
    bQl[ks] = *(const bf16x8*)(Ql + qa);
  }

  f32x4 oacc[4] = {};
  float m = -3e38f, lsum = 0.f;

  // staging: 24 wave-issues of 1KB (8 rows x 128B); wave w does j = w*12..+11.
  // lane l writes LDS linear (row = sub*8 + l/8, colb = (l&7)*16); source col
  // pre-swizzled: srcb = colb ^ ((row&7)<<4)  ->  elem off = ((l&7)^(l>>3))*8
  const int srow = l >> 3;
  const int se   = ((l & 7) ^ srow) << 3;

  for (int kt = 0; kt < nkt; ++kt) {
#pragma unroll
    for (int ii = 0; ii < 12; ++ii) {
      const int j = w * 12 + ii;
      const int buf = j >> 3, sub = j & 7;
      const int row = sub * 8 + srow;
      const ushort* src;
      if (buf == 0)      src = Kh + base + (size_t)(kt*64 + row) * HDIM + se;
      else if (buf == 1) src = Kl + base + (size_t)(kt*64 + row) * HDIM + se;
      else               src = Vt + ((size_t)bh * HDIM + row) * S_LEN + kt*64 + se;
      async16(src, &sKV[buf*4096 + sub*512]);
    }
    asm volatile("s_waitcnt vmcnt(0)" ::: "memory");
    __syncthreads();

    // QK^T (swapped): A = K rows, B = Q cols
    f32x4 s[4] = {};
#pragma unroll
    for (int ks = 0; ks < 2; ++ks) {
      const int cb = (((ks*64 + g*16) ^ ((q & 7) << 4)) >> 1);
#pragma unroll
      for (int n = 0; n < 4; ++n) {
        const int rb = (n*16 + q) * 64;
        bf16x8 kh = *(const bf16x8*)&sKV[rb + cb];
        bf16x8 kl = *(const bf16x8*)&sKV[4096 + rb + cb];
        s[n] = mfma16(kh, bQh[ks], s[n]);
        s[n] = mfma16(kl, bQh[ks], s[n]);
        s[n] = mfma16(kh, bQl[ks], s[n]);
      }
    }
    if (kt == nkt - 1) {  // causal mask on last tile
      const int qg = q0 + q;
#pragma unroll
      for (int n = 0; n < 4; ++n)
#pragma unroll
        for (int r = 0; r < 4; ++r) {
          int kg = kt*64 + n*16 + g*4 + r;
          if (kg > qg) s[n][r] = -1e30f;
        }
    }
    // softmax: 16 in-lane + xor16/xor32
    float pm = -3e38f;
#pragma unroll
    for (int n = 0; n < 4; ++n)
#pragma unroll
      for (int r = 0; r < 4; ++r) pm = fmaxf(pm, s[n][r]);
    pm = fmaxf(pm, __shfl_xor(pm, 16));
    pm = fmaxf(pm, __shfl_xor(pm, 32));
    float mnew = fmaxf(m, pm);
    float sc = __expf(m - mnew);
    m = mnew;
    float rs = 0.f;
#pragma unroll
    for (int n = 0; n < 4; ++n)
#pragma unroll
      for (int r = 0; r < 4; ++r) {
        float pe = __expf(s[n][r] - mnew);
        s[n][r] = pe;
        rs += pe;
      }
    rs += __shfl_xor(rs, 16);
    rs += __shfl_xor(rs, 32);
    lsum = lsum * sc + rs;

    // P^T -> per-wave LDS
#pragma unroll
    for (int n = 0; n < 4; ++n) {
      *(unsigned*)&Plds[w][q][n*16 + g*4]     = pack_bf16(s[n][0], s[n][1]);
      *(unsigned*)&Plds[w][q][n*16 + g*4 + 2] = pack_bf16(s[n][2], s[n][3]);
    }
    float scr[4];
#pragma unroll
    for (int r = 0; r < 4; ++r) scr[r] = __shfl(sc, g*4 + r);
#pragma unroll
    for (int dt = 0; dt < 4; ++dt)
#pragma unroll
      for (int r = 0; r < 4; ++r) oacc[dt][r] *= scr[r];

    // PV from staged V
#pragma unroll
    for (int ks = 0; ks < 2; ++ks) {
      bf16x8 ap = *(const bf16x8*)&Plds[w][q][ks*32 + g*8];
      const int cb = (((ks*64 + g*16) ^ ((q & 7) << 4)) >> 1);
#pragma unroll
      for (int dt = 0; dt < 4; ++dt) {
        bf16x8 bv = *(const bf16x8*)&sKV[8192 + (dt*16 + q)*64 + cb];
        oacc[dt] = mfma16(ap, bv, oacc[dt]);
      }
    }
    __syncthreads();   // all waves done reading sKV before next stage
  }

  float lsr[4];
#pragma unroll
  for (int r = 0; r < 4; ++r) lsr[r] = __shfl(lsum, g*4 + r);
  const int b = bh >> 4, h = bh & 15;
#pragma unroll
  for (int dt = 0; dt < 4; ++dt)
#pragma unroll
    for (int r = 0; r < 4; ++r) {
      int qg = q0 + g*4 + r;
      float o = oacc[dt][r] / lsr[r];
      size_t row = (size_t)b * S_LEN + qg;
      int col = h * HDIM + dt*16 + q;
      ushort hv = f2bf(o);
      Oh[row * DM + col] = hv;
      Ol[row * DM + col] = f2bf(o - bf2f(hv));
    }
}

extern "C" void kernel_launch(void* const* d_in, const int* in_sizes, int n_in,
                              void* d_out, int out_size, void* d_ws, size_t ws_size,
                              hipStream_t stream)
{
  const float* x  = (const float*)d_in[0];
  const float* Wq = (const float*)d_in[2];
  const float* bq = (const float*)d_in[3];
  const float* Wk = (const float*)d_in[4];
  const float* bk = (const float*)d_in[5];
  const float* Wv = (const float*)d_in[6];
  const float* bv = (const float*)d_in[7];
  const float* Wo = (const float*)d_in[8];
  const float* bo = (const float*)d_in[9];
  float* out = (float*)d_out;

  char* ws = (char*)d_ws;
  size_t off = 0;
  auto alloc = [&](size_t bytes) { char* p = ws + off; off += bytes; return p; };
  const size_t XN = (size_t)NROWS * DM;
  const size_t WN = (size_t)DM * DM;

  ushort* Xh  = (ushort*)alloc(XN * 2);
  ushort* Xl  = (ushort*)alloc(XN * 2);
  ushort* Wh  = (ushort*)alloc(3 * WN * 2);
  ushort* Wl  = (ushort*)alloc(3 * WN * 2);
  ushort* Woh = (ushort*)alloc(WN * 2);
  ushort* Wol = (ushort*)alloc(WN * 2);
  ushort* Qh  = (ushort*)alloc(XN * 2);
  ushort* Ql  = (ushort*)alloc(XN * 2);
  ushort* Kh  = (ushort*)alloc(XN * 2);
  ushort* Kl  = (ushort*)alloc(XN * 2);
  ushort* Vb  = (ushort*)alloc(XN * 2);
  ushort* Vt  = (ushort*)alloc(XN * 2);
  ushort* Oh  = (ushort*)alloc(XN * 2);
  ushort* Ol  = (ushort*)alloc(XN * 2);
  (void)ws_size; (void)in_sizes; (void)n_in; (void)out_size;

  split_kernel<<<(int)(XN/4/256), 256, 0, stream>>>(x,  Xh, Xl, (int)(XN/4));
  split_kernel<<<(int)(WN/4/256), 256, 0, stream>>>(Wq, Wh,        Wl,        (int)(WN/4));
  split_kernel<<<(int)(WN/4/256), 256, 0, stream>>>(Wk, Wh + WN,   Wl + WN,   (int)(WN/4));
  split_kernel<<<(int)(WN/4/256), 256, 0, stream>>>(Wv, Wh + 2*WN, Wl + 2*WN, (int)(WN/4));
  split_kernel<<<(int)(WN/4/256), 256, 0, stream>>>(Wo, Woh, Wol, (int)(WN/4));

  gemm_split<0><<<dim3(24, 32), 256, 0, stream>>>(Xh, Xl, Wh, Wl, bq, bk, bv,
                                                  nullptr, Qh, Ql, Kh, Kl, Vb, 3072);
  transpose_v<<<dim3(32, 32), 256, 0, stream>>>(Vb, Vt);
  attn_kernel<<<2048, 128, 0, stream>>>(Qh, Ql, Kh, Kl, Vt, Oh, Ol);
  gemm_split<1><<<dim3(8, 32), 256, 0, stream>>>(Oh, Ol, Woh, Wol, bo, nullptr, nullptr,
                                                 out, nullptr, nullptr, nullptr,
                                                 nullptr, nullptr, 1024);
}

// Round 4
// 135.476 us; speedup vs baseline: 5.0002x; 1.6542x over previous
//
#include <hip/hip_runtime.h>

#define S_LEN 2048
#define DM    1024
#define NHEAD 16
#define HDIM  64
#define NB    2
#define NROWS (NB * S_LEN)   // 4096

using f32x4  = __attribute__((ext_vector_type(4))) float;
using f16x8  = __attribute__((ext_vector_type(8))) _Float16;

__device__ __forceinline__ ushort f2h(float f) {
  return __builtin_bit_cast(ushort, (_Float16)f);
}
__device__ __forceinline__ unsigned pack_f16(float a, float b) {
  return (unsigned)f2h(a) | ((unsigned)f2h(b) << 16);
}
__device__ __forceinline__ f32x4 mfma16(f16x8 a, f16x8 b, f32x4 c) {
  return __builtin_amdgcn_mfma_f32_16x16x32_f16(a, b, c, 0, 0, 0);
}
__device__ __forceinline__ void async16(const ushort* g, ushort* l) {
  __builtin_amdgcn_global_load_lds(
      (const __attribute__((address_space(1))) unsigned*)g,
      (__attribute__((address_space(3))) unsigned*)l, 16, 0, 0);
}

// ---------------- fp32 -> fp16 ----------------
__global__ void tohalf_kernel(const float* __restrict__ in, ushort* __restrict__ out,
                              int n4) {
  int i = blockIdx.x * 256 + threadIdx.x;
  if (i >= n4) return;
  float4 v = ((const float4*)in)[i];
  ((ushort4*)out)[i] = make_ushort4(f2h(v.x), f2h(v.y), f2h(v.z), f2h(v.w));
}

// ---------------- fp16 NT GEMM: C = A[M,K] * (B[N,K])^T ----------------
// 128x128 tile, BK=64, 256 thr (4 waves 2x2). Double-buffered LDS staged via
// global_load_lds(16B): linear LDS dest, XOR-swizzle (byte ^= (row&7)<<4)
// pre-applied on the global source column; ds_read_b128 applies same XOR.
// 2-phase: stage(next) -> compute(cur) -> vmcnt(0)+barrier.
// EPI 0: QKV epilogue (N=3072): cols [0,1024)->Q, [1024,2048)->K, [2048,3072)->V,
//        scattered to [B,H,S,64] fp16, + biases.  EPI 1: fp32 out = acc + bias.
template<int EPI>
__global__ __launch_bounds__(256, 2)
void gemm_half(const ushort* __restrict__ A, const ushort* __restrict__ B,
               const float* __restrict__ biasQ, const float* __restrict__ biasK,
               const float* __restrict__ biasV,
               float* __restrict__ outF,
               ushort* __restrict__ Q, ushort* __restrict__ Kd,
               ushort* __restrict__ V, int Ncols)
{
  constexpr int KD = 1024;
  __shared__ ushort sA[2][128 * 64];
  __shared__ ushort sB[2][128 * 64];
  const int t = threadIdx.x;
  const int w = t >> 6, l = t & 63;
  const int lr = l >> 4, lc = l & 15;
  const int wr = w >> 1, wc = w & 1;
  const int nwg = gridDim.x * gridDim.y;
  const int lin = blockIdx.y * gridDim.x + blockIdx.x;
  const int per8 = nwg >> 3;
  const int swz = (lin & 7) * per8 + (lin >> 3);
  const int i0 = (swz / gridDim.x) * 128, j0 = (swz % gridDim.x) * 128;

  const int srow = l >> 3;                 // 0..7
  const int se   = ((l & 7) ^ srow) << 3;  // pre-swizzled source elem offset

  auto stage = [&](int buf, int k0) {
#pragma unroll
    for (int j = 0; j < 4; ++j) {
      const int c = w * 4 + j;             // chunk: rows c*8..c*8+7
      async16(A + (size_t)(i0 + c * 8 + srow) * KD + k0 + se, &sA[buf][c * 512]);
      async16(B + (size_t)(j0 + c * 8 + srow) * KD + k0 + se, &sB[buf][c * 512]);
    }
  };

  f32x4 acc[4][4] = {};
  stage(0, 0);
  asm volatile("s_waitcnt vmcnt(0)" ::: "memory");
  __syncthreads();
  int cur = 0;
  for (int k0 = 0; k0 < KD; k0 += 64) {
    if (k0 + 64 < KD) stage(cur ^ 1, k0 + 64);
#pragma unroll
    for (int kk = 0; kk < 2; ++kk) {
      f16x8 a[4], b[4];
#pragma unroll
      for (int m = 0; m < 4; ++m) {
        const int row = wr * 64 + m * 16 + lc;
        const int cb = (kk * 64 + lr * 16) ^ ((lc & 7) << 4);
        a[m] = *(const f16x8*)&sA[cur][row * 64 + (cb >> 1)];
      }
#pragma unroll
      for (int n = 0; n < 4; ++n) {
        const int row = wc * 64 + n * 16 + lc;
        const int cb = (kk * 64 + lr * 16) ^ ((lc & 7) << 4);
        b[n] = *(const f16x8*)&sB[cur][row * 64 + (cb >> 1)];
      }
#pragma unroll
      for (int m = 0; m < 4; ++m)
#pragma unroll
        for (int n = 0; n < 4; ++n)
          acc[m][n] = mfma16(a[m], b[n], acc[m][n]);
    }
    asm volatile("s_waitcnt vmcnt(0)" ::: "memory");
    __syncthreads();
    cur ^= 1;
  }

#pragma unroll
  for (int m = 0; m < 4; ++m)
#pragma unroll
    for (int n = 0; n < 4; ++n)
#pragma unroll
      for (int r = 0; r < 4; ++r) {
        int i = i0 + wr * 64 + m * 16 + lr * 4 + r;
        int j = j0 + wc * 64 + n * 16 + lc;
        float v = acc[m][n][r];
        if constexpr (EPI == 0) {
          int region = j >> 10;
          int jc = j & 1023;
          int h = jc >> 6, d = jc & 63;
          int b = i >> 11, s = i & 2047;
          size_t idx = ((size_t)(b * NHEAD + h) * S_LEN + s) * HDIM + d;
          if (region == 0)      Q[idx]  = f2h(v + biasQ[jc]);
          else if (region == 1) Kd[idx] = f2h(v + biasK[jc]);
          else                  V[idx]  = f2h(v + biasV[jc]);
        } else {
          outF[(size_t)i * Ncols + j] = v + biasQ[j];
        }
      }
}

// ---------------- V [B,H,S,64] -> Vt [B,H,64,S] ----------------
__global__ void transpose_v(const ushort* __restrict__ V, ushort* __restrict__ Vt) {
  __shared__ ushort tile[64][72];
  const int st = blockIdx.x, bh = blockIdx.y;
  const int t = threadIdx.x;
#pragma unroll
  for (int jj = 0; jj < 2; ++jj) {
    int c = jj * 256 + t;
    int rr = c >> 3, cc = (c & 7) * 8;
    *(uint4*)&tile[rr][cc] =
        *(const uint4*)&V[(((size_t)bh * S_LEN) + st * 64 + rr) * HDIM + cc];
  }
  __syncthreads();
#pragma unroll
  for (int jj = 0; jj < 2; ++jj) {
    int c = jj * 256 + t;
    int d = c >> 3, s8 = (c & 7) * 8;
    alignas(16) ushort vals[8];
#pragma unroll
    for (int u = 0; u < 8; ++u) vals[u] = tile[s8 + u][d];
    *(uint4*)&Vt[(((size_t)bh * HDIM) + d) * S_LEN + st * 64 + s8] = *(uint4*)vals;
  }
}

// ---------------- flash attention (fp16, double-buffered K/V staging) -------
// 2048 blocks x 128 thr (2 waves). v = 63-(lin>>5) longest-first, bh = lin&31.
// Per kt: K,V 64x64 fp16 tiles in LDS via global_load_lds(16B), XOR-swizzled
// via pre-swizzled source (rule #21), double-buffered (stage kt+1 during kt).
// Swapped QK^T (s = mfma(K,Q)): softmax fully in-register + 2 shuffles.
__global__ __launch_bounds__(128, 2)
void attn_kernel(const ushort* __restrict__ Qp, const ushort* __restrict__ Kp,
                 const ushort* __restrict__ Vt,
                 ushort* __restrict__ O)
{
  __shared__ ushort sKV[2][2 * 64 * 64];   // [buf][Kh tile | V tile]
  __shared__ ushort Plds[2][16][72];
  const int lin = blockIdx.x;
  const int v  = 63 - (lin >> 5);
  const int bh = lin & 31;
  const int t = threadIdx.x, w = t >> 6, l = t & 63;
  const int g = l >> 4, q = l & 15;
  const size_t base = (size_t)bh * S_LEN * HDIM;
  const int q0 = v * 32 + w * 16;
  const int nkt = (v >> 1) + 1;

  const int srow = l >> 3;
  const int se   = ((l & 7) ^ srow) << 3;

  auto stage = [&](int buf, int kt) {
#pragma unroll
    for (int ii = 0; ii < 8; ++ii) {
      const int c = w * 8 + ii;
      const int sel = c >> 3, sub = c & 7;   // wave0: K, wave1: V
      const ushort* src =
          sel == 0 ? Kp + base + (size_t)(kt * 64 + sub * 8 + srow) * HDIM + se
                   : Vt + ((size_t)bh * HDIM + sub * 8 + srow) * S_LEN + kt * 64 + se;
      async16(src, &sKV[buf][sel * 4096 + sub * 512]);
    }
  };

  // Q as B-fragments (rows q0+q)
  f16x8 bQ[2];
#pragma unroll
  for (int ks = 0; ks < 2; ++ks)
    bQ[ks] = *(const f16x8*)(Qp + base + (size_t)(q0 + q) * HDIM + ks * 32 + g * 8);

  f32x4 oacc[4] = {};
  float m = -3e38f, lsum = 0.f;

  stage(0, 0);
  asm volatile("s_waitcnt vmcnt(0)" ::: "memory");
  __syncthreads();
  int cur = 0;

  for (int kt = 0; kt < nkt; ++kt) {
    if (kt + 1 < nkt) stage(cur ^ 1, kt + 1);

    // QK^T (swapped): A = K rows, B = Q cols
    f32x4 s[4] = {};
#pragma unroll
    for (int ks = 0; ks < 2; ++ks) {
      const int cb = (((ks * 64 + g * 16) ^ ((q & 7) << 4)) >> 1);
#pragma unroll
      for (int n = 0; n < 4; ++n) {
        f16x8 kf = *(const f16x8*)&sKV[cur][(n * 16 + q) * 64 + cb];
        s[n] = mfma16(kf, bQ[ks], s[n]);
      }
    }
    if (kt == nkt - 1) {   // causal mask on diagonal tile
      const int qg = q0 + q;
#pragma unroll
      for (int n = 0; n < 4; ++n)
#pragma unroll
        for (int r = 0; r < 4; ++r) {
          int kg = kt * 64 + n * 16 + g * 4 + r;
          if (kg > qg) s[n][r] = -1e30f;
        }
    }
    // softmax: 16 in-lane + xor16/xor32
    float pm = -3e38f;
#pragma unroll
    for (int n = 0; n < 4; ++n)
#pragma unroll
      for (int r = 0; r < 4; ++r) pm = fmaxf(pm, s[n][r]);
    pm = fmaxf(pm, __shfl_xor(pm, 16));
    pm = fmaxf(pm, __shfl_xor(pm, 32));
    float mnew = fmaxf(m, pm);
    float sc = __expf(m - mnew);
    m = mnew;
    float rs = 0.f;
#pragma unroll
    for (int n = 0; n < 4; ++n)
#pragma unroll
      for (int r = 0; r < 4; ++r) {
        float pe = __expf(s[n][r] - mnew);
        s[n][r] = pe;
        rs += pe;
      }
    rs += __shfl_xor(rs, 16);
    rs += __shfl_xor(rs, 32);
    lsum = lsum * sc + rs;

    // P^T -> per-wave LDS (fp16 pairs)
#pragma unroll
    for (int n = 0; n < 4; ++n) {
      *(unsigned*)&Plds[w][q][n * 16 + g * 4]     = pack_f16(s[n][0], s[n][1]);
      *(unsigned*)&Plds[w][q][n * 16 + g * 4 + 2] = pack_f16(s[n][2], s[n][3]);
    }
    float scr[4];
#pragma unroll
    for (int r = 0; r < 4; ++r) scr[r] = __shfl(sc, g * 4 + r);
#pragma unroll
    for (int dt = 0; dt < 4; ++dt)
#pragma unroll
      for (int r = 0; r < 4; ++r) oacc[dt][r] *= scr[r];

    // PV from staged V
#pragma unroll
    for (int ks = 0; ks < 2; ++ks) {
      f16x8 ap = *(const f16x8*)&Plds[w][q][ks * 32 + g * 8];
      const int cb = (((ks * 64 + g * 16) ^ ((q & 7) << 4)) >> 1);
#pragma unroll
      for (int dt = 0; dt < 4; ++dt) {
        f16x8 bv = *(const f16x8*)&sKV[cur][4096 + (dt * 16 + q) * 64 + cb];
        oacc[dt] = mfma16(ap, bv, oacc[dt]);
      }
    }
    asm volatile("s_waitcnt vmcnt(0)" ::: "memory");
    __syncthreads();
    cur ^= 1;
  }

  float lsr[4];
#pragma unroll
  for (int r = 0; r < 4; ++r) lsr[r] = __shfl(lsum, g * 4 + r);
  const int b = bh >> 4, h = bh & 15;
#pragma unroll
  for (int dt = 0; dt < 4; ++dt)
#pragma unroll
    for (int r = 0; r < 4; ++r) {
      int qg = q0 + g * 4 + r;
      float o = oacc[dt][r] / lsr[r];
      O[((size_t)b * S_LEN + qg) * DM + h * HDIM + dt * 16 + q] = f2h(o);
    }
}

extern "C" void kernel_launch(void* const* d_in, const int* in_sizes, int n_in,
                              void* d_out, int out_size, void* d_ws, size_t ws_size,
                              hipStream_t stream)
{
  const float* x  = (const float*)d_in[0];
  const float* Wq = (const float*)d_in[2];
  const float* bq = (const float*)d_in[3];
  const float* Wk = (const float*)d_in[4];
  const float* bk = (const float*)d_in[5];
  const float* Wv = (const float*)d_in[6];
  const float* bv = (const float*)d_in[7];
  const float* Wo = (const float*)d_in[8];
  const float* bo = (const float*)d_in[9];
  float* out = (float*)d_out;

  char* ws = (char*)d_ws;
  size_t off = 0;
  auto alloc = [&](size_t bytes) { char* p = ws + off; off += bytes; return p; };
  const size_t XN = (size_t)NROWS * DM;   // 4,194,304
  const size_t WN = (size_t)DM * DM;      // 1,048,576

  ushort* Xh  = (ushort*)alloc(XN * 2);
  ushort* Wh  = (ushort*)alloc(3 * WN * 2);   // packed Wq|Wk|Wv
  ushort* Woh = (ushort*)alloc(WN * 2);
  ushort* Qb  = (ushort*)alloc(XN * 2);
  ushort* Kb  = (ushort*)alloc(XN * 2);
  ushort* Vb  = (ushort*)alloc(XN * 2);
  ushort* Vt  = (ushort*)alloc(XN * 2);
  ushort* Ob  = (ushort*)alloc(XN * 2);
  (void)ws_size; (void)in_sizes; (void)n_in; (void)out_size;

  tohalf_kernel<<<(int)(XN/4/256), 256, 0, stream>>>(x,  Xh, (int)(XN/4));
  tohalf_kernel<<<(int)(WN/4/256), 256, 0, stream>>>(Wq, Wh,          (int)(WN/4));
  tohalf_kernel<<<(int)(WN/4/256), 256, 0, stream>>>(Wk, Wh + WN,     (int)(WN/4));
  tohalf_kernel<<<(int)(WN/4/256), 256, 0, stream>>>(Wv, Wh + 2*WN,   (int)(WN/4));
  tohalf_kernel<<<(int)(WN/4/256), 256, 0, stream>>>(Wo, Woh, (int)(WN/4));

  gemm_half<0><<<dim3(24, 32), 256, 0, stream>>>(Xh, Wh, bq, bk, bv,
                                                 nullptr, Qb, Kb, Vb, 3072);
  transpose_v<<<dim3(32, 32), 256, 0, stream>>>(Vb, Vt);
  attn_kernel<<<2048, 128, 0, stream>>>(Qb, Kb, Vt, Ob);
  gemm_half<1><<<dim3(8, 32), 256, 0, stream>>>(Ob, Woh, bo, nullptr, nullptr,
                                                out, nullptr, nullptr, nullptr, 1024);
}

// Round 5
// 122.633 us; speedup vs baseline: 5.5239x; 1.1047x over previous
//
#include <hip/hip_runtime.h>

#define S_LEN 2048
#define DM    1024
#define NHEAD 16
#define HDIM  64
#define NB    2
#define NROWS (NB * S_LEN)   // 4096
#define RCP_LN2 1.44269504f

using f32x4  = __attribute__((ext_vector_type(4))) float;
using f16x8  = __attribute__((ext_vector_type(8))) _Float16;
using f16x2  = __attribute__((ext_vector_type(2))) _Float16;

__device__ __forceinline__ ushort f2h(float f) {
  return __builtin_bit_cast(ushort, (_Float16)f);
}
__device__ __forceinline__ unsigned pkrtz(float a, float b) {
  return __builtin_bit_cast(unsigned, __builtin_amdgcn_cvt_pkrtz(a, b));
}
__device__ __forceinline__ f32x4 mfma16(f16x8 a, f16x8 b, f32x4 c) {
  return __builtin_amdgcn_mfma_f32_16x16x32_f16(a, b, c, 0, 0, 0);
}
__device__ __forceinline__ void async16(const ushort* g, ushort* l) {
  __builtin_amdgcn_global_load_lds(
      (const __attribute__((address_space(1))) unsigned*)g,
      (__attribute__((address_space(3))) unsigned*)l, 16, 0, 0);
}

// ---------------- fused fp32 -> fp16 for x, Wq, Wk, Wv, Wo ----------------
__global__ void tohalf5(const float* __restrict__ x,  const float* __restrict__ wq,
                        const float* __restrict__ wk, const float* __restrict__ wv,
                        const float* __restrict__ wo,
                        ushort* __restrict__ Xh, ushort* __restrict__ Wh,
                        ushort* __restrict__ Woh) {
  constexpr int X4 = (NROWS * DM) / 4;       // 1,048,576
  constexpr int W4 = (DM * DM) / 4;          // 262,144
  const size_t WN = (size_t)DM * DM;
  int i = blockIdx.x * 256 + threadIdx.x;
  const float4* src; ushort4* dst; int k;
  if (i < X4)               { src = (const float4*)x;  dst = (ushort4*)Xh;        k = i; }
  else if (i < X4 + W4)     { src = (const float4*)wq; dst = (ushort4*)Wh;        k = i - X4; }
  else if (i < X4 + 2*W4)   { src = (const float4*)wk; dst = (ushort4*)(Wh+WN);   k = i - X4 - W4; }
  else if (i < X4 + 3*W4)   { src = (const float4*)wv; dst = (ushort4*)(Wh+2*WN); k = i - X4 - 2*W4; }
  else                      { src = (const float4*)wo; dst = (ushort4*)Woh;       k = i - X4 - 3*W4; }
  float4 v = src[k];
  dst[k] = make_ushort4(f2h(v.x), f2h(v.y), f2h(v.z), f2h(v.w));
}

// ---------------- fp16 NT GEMM: C = A[M,K] * (B[N,K])^T ----------------
// BM = MFRAG*32, BN = NFRAG*32 tile, BK=64, 256 thr (4 waves 2x2).
// Single-buffer LDS, global_load_lds(16B), XOR-swizzle via pre-swizzled global
// source column (rule #21); 2 barriers per K-step (m97 structure).
// EPI 0: QKV epilogue (N=3072): Q (x log2e) -> [B,H,S,64], K -> [B,H,S,64],
//        V -> transposed [B,H,64,S] (ushort4-packed).  EPI 1: fp32 out + bias.
template<int EPI, int MFRAG, int NFRAG>
__global__ __launch_bounds__(256, 4)
void gemm_half(const ushort* __restrict__ A, const ushort* __restrict__ B,
               const float* __restrict__ biasQ, const float* __restrict__ biasK,
               const float* __restrict__ biasV,
               float* __restrict__ outF,
               ushort* __restrict__ Q, ushort* __restrict__ Kd,
               ushort* __restrict__ Vt, int Ncols)
{
  constexpr int KD = 1024;
  constexpr int BM = MFRAG * 32, BN = NFRAG * 32;
  constexpr int NCH = (BM + BN) / 8;     // 8-row x 64-col chunks per K-step
  constexpr int CPW = NCH / 4;
  __shared__ ushort sL[(BM + BN) * 64];  // [A tile | B tile]
  const int t = threadIdx.x;
  const int w = t >> 6, l = t & 63;
  const int lr = l >> 4, lc = l & 15;
  const int wr = w >> 1, wc = w & 1;
  const int nwg = gridDim.x * gridDim.y;
  const int lin = blockIdx.y * gridDim.x + blockIdx.x;
  const int per8 = nwg >> 3;
  const int swz = (lin & 7) * per8 + (lin >> 3);
  const int i0 = (swz / gridDim.x) * BM, j0 = (swz % gridDim.x) * BN;

  const int srow = l >> 3;                 // 0..7
  const int se   = ((l & 7) ^ srow) << 3;  // pre-swizzled source elem offset

  f32x4 acc[MFRAG][NFRAG] = {};

  for (int k0 = 0; k0 < KD; k0 += 64) {
#pragma unroll
    for (int ii = 0; ii < CPW; ++ii) {
      const int c = w * CPW + ii;
      const ushort* src = (c < BM / 8)
          ? A + (size_t)(i0 + c * 8 + srow) * KD + k0 + se
          : B + (size_t)(j0 + (c - BM / 8) * 8 + srow) * KD + k0 + se;
      async16(src, &sL[c * 512]);
    }
    asm volatile("s_waitcnt vmcnt(0)" ::: "memory");
    __syncthreads();
#pragma unroll
    for (int kk = 0; kk < 2; ++kk) {
      const int cb = (kk * 64 + lr * 16) ^ ((lc & 7) << 4);
      f16x8 a[MFRAG], b[NFRAG];
#pragma unroll
      for (int m = 0; m < MFRAG; ++m)
        a[m] = *(const f16x8*)&sL[(wr * MFRAG * 16 + m * 16 + lc) * 64 + (cb >> 1)];
#pragma unroll
      for (int n = 0; n < NFRAG; ++n)
        b[n] = *(const f16x8*)&sL[BM * 64 + (wc * NFRAG * 16 + n * 16 + lc) * 64 + (cb >> 1)];
#pragma unroll
      for (int m = 0; m < MFRAG; ++m)
#pragma unroll
        for (int n = 0; n < NFRAG; ++n)
          acc[m][n] = mfma16(a[m], b[n], acc[m][n]);
    }
    __syncthreads();
  }

#pragma unroll
  for (int m = 0; m < MFRAG; ++m)
#pragma unroll
    for (int n = 0; n < NFRAG; ++n) {
      const int jbase = j0 + wc * NFRAG * 16 + n * 16;   // + lc per element
      const int ibase = i0 + wr * MFRAG * 16 + m * 16 + lr * 4;
      if constexpr (EPI == 0) {
        const int region = jbase >> 10;
        const int jc0 = jbase & 1023;
        const int h = jc0 >> 6, d0 = jc0 & 63;
        const int b = ibase >> 11, s0 = ibase & 2047;
        const size_t bh = (size_t)(b * NHEAD + h);
        if (region == 0) {
          float bb = biasQ[jc0 + lc];
#pragma unroll
          for (int r = 0; r < 4; ++r)
            Q[(bh * S_LEN + s0 + r) * HDIM + d0 + lc] =
                f2h((acc[m][n][r] + bb) * RCP_LN2);
        } else if (region == 1) {
          float bb = biasK[jc0 + lc];
#pragma unroll
          for (int r = 0; r < 4; ++r)
            Kd[(bh * S_LEN + s0 + r) * HDIM + d0 + lc] = f2h(acc[m][n][r] + bb);
        } else {
          float bb = biasV[jc0 + lc];
          ushort4 pv = make_ushort4(f2h(acc[m][n][0] + bb), f2h(acc[m][n][1] + bb),
                                    f2h(acc[m][n][2] + bb), f2h(acc[m][n][3] + bb));
          *(ushort4*)&Vt[(bh * HDIM + d0 + lc) * S_LEN + s0] = pv;
        }
      } else {
#pragma unroll
        for (int r = 0; r < 4; ++r)
          outF[(size_t)(ibase + r) * Ncols + jbase + lc] =
              acc[m][n][r] + biasQ[jbase + lc];
      }
    }
}

// ---------------- flash attention (fp16, single-buffer staged K/V) ----------
// 2048 blocks x 128 thr (2 waves). v = 63-(lin>>5) longest-first, bh = lin&31.
// LDS 21KB -> 7 blocks/CU (TLP hides staging latency; T14-null logic).
// Q pre-scaled by log2e -> softmax in exp2 units. T13 defer-max (THR=8).
// Swapped QK^T keeps softmax in-register (2 shuffles per reduce).
__global__ __launch_bounds__(128, 4)
void attn_kernel(const ushort* __restrict__ Qp, const ushort* __restrict__ Kp,
                 const ushort* __restrict__ Vt, ushort* __restrict__ O)
{
  __shared__ ushort sKV[2 * 64 * 64];   // [K tile | V tile], rows XOR-swizzled
  __shared__ ushort Plds[2][16][72];
  const int lin = blockIdx.x;
  const int v  = 63 - (lin >> 5);
  const int bh = lin & 31;
  const int t = threadIdx.x, w = t >> 6, l = t & 63;
  const int g = l >> 4, q = l & 15;
  const size_t base = (size_t)bh * S_LEN * HDIM;
  const int q0 = v * 32 + w * 16;
  const int nkt = (v >> 1) + 1;

  const int srow = l >> 3;
  const int se   = ((l & 7) ^ srow) << 3;

  // Q as B-fragments (rows q0+q); already scaled by log2e
  f16x8 bQ[2];
#pragma unroll
  for (int ks = 0; ks < 2; ++ks)
    bQ[ks] = *(const f16x8*)(Qp + base + (size_t)(q0 + q) * HDIM + ks * 32 + g * 8);

  f32x4 oacc[4] = {};
  float m = -3e38f, lsum = 0.f;

  for (int kt = 0; kt < nkt; ++kt) {
    // stage K (wave0) and V (wave1) 64x64 tiles
#pragma unroll
    for (int ii = 0; ii < 8; ++ii) {
      const int c = w * 8 + ii;
      const int sel = c >> 3, sub = c & 7;
      const ushort* src =
          sel == 0 ? Kp + base + (size_t)(kt * 64 + sub * 8 + srow) * HDIM + se
                   : Vt + ((size_t)bh * HDIM + sub * 8 + srow) * S_LEN + kt * 64 + se;
      async16(src, &sKV[sel * 4096 + sub * 512]);
    }
    asm volatile("s_waitcnt vmcnt(0)" ::: "memory");
    __syncthreads();

    // QK^T (swapped): A = K rows, B = Q cols
    f32x4 s[4] = {};
#pragma unroll
    for (int ks = 0; ks < 2; ++ks) {
      const int cb = (((ks * 64 + g * 16) ^ ((q & 7) << 4)) >> 1);
#pragma unroll
      for (int n = 0; n < 4; ++n) {
        f16x8 kf = *(const f16x8*)&sKV[(n * 16 + q) * 64 + cb];
        s[n] = mfma16(kf, bQ[ks], s[n]);
      }
    }
    if (kt == nkt - 1) {   // causal mask on diagonal tile
      const int qg = q0 + q;
#pragma unroll
      for (int n = 0; n < 4; ++n)
#pragma unroll
        for (int r = 0; r < 4; ++r) {
          int kg = kt * 64 + n * 16 + g * 4 + r;
          if (kg > qg) s[n][r] = -1e30f;
        }
    }
    // column max (log2 units): 16 in-lane + xor16/xor32
    float pm = -3e38f;
#pragma unroll
    for (int n = 0; n < 4; ++n) {
      pm = fmaxf(pm, fmaxf(fmaxf(s[n][0], s[n][1]), fmaxf(s[n][2], s[n][3])));
    }
    pm = fmaxf(pm, __shfl_xor(pm, 16));
    pm = fmaxf(pm, __shfl_xor(pm, 32));
    // T13 defer-max: only rescale when max grew by > 8 (P bounded by 2^8)
    if (__any(pm > m + 8.0f)) {
      float mnew = fmaxf(m, pm);
      float sc = exp2f(m - mnew);
      m = mnew;
      float scr[4];
#pragma unroll
      for (int r = 0; r < 4; ++r) scr[r] = __shfl(sc, g * 4 + r);
#pragma unroll
      for (int dt = 0; dt < 4; ++dt)
#pragma unroll
        for (int r = 0; r < 4; ++r) oacc[dt][r] *= scr[r];
      lsum *= sc;
    }
    float rs = 0.f;
#pragma unroll
    for (int n = 0; n < 4; ++n)
#pragma unroll
      for (int r = 0; r < 4; ++r) {
        float pe = exp2f(s[n][r] - m);
        s[n][r] = pe;
        rs += pe;
      }
    rs += __shfl_xor(rs, 16);
    rs += __shfl_xor(rs, 32);
    lsum += rs;

    // P^T -> per-wave LDS (packed fp16 pairs, 8B writes)
#pragma unroll
    for (int n = 0; n < 4; ++n) {
      uint2 pk = make_uint2(pkrtz(s[n][0], s[n][1]), pkrtz(s[n][2], s[n][3]));
      *(uint2*)&Plds[w][q][n * 16 + g * 4] = pk;
    }
    // PV from staged V
#pragma unroll
    for (int ks = 0; ks < 2; ++ks) {
      f16x8 ap = *(const f16x8*)&Plds[w][q][ks * 32 + g * 8];
      const int cb = (((ks * 64 + g * 16) ^ ((q & 7) << 4)) >> 1);
#pragma unroll
      for (int dt = 0; dt < 4; ++dt) {
        f16x8 bv = *(const f16x8*)&sKV[4096 + (dt * 16 + q) * 64 + cb];
        oacc[dt] = mfma16(ap, bv, oacc[dt]);
      }
    }
    __syncthreads();   // all waves done with sKV before next stage
  }

  float lsr[4];
#pragma unroll
  for (int r = 0; r < 4; ++r)
    lsr[r] = __builtin_amdgcn_rcpf(__shfl(lsum, g * 4 + r));
  const int b = bh >> 4, h = bh & 15;
#pragma unroll
  for (int dt = 0; dt < 4; ++dt)
#pragma unroll
    for (int r = 0; r < 4; ++r) {
      int qg = q0 + g * 4 + r;
      O[((size_t)b * S_LEN + qg) * DM + h * HDIM + dt * 16 + q] =
          f2h(oacc[dt][r] * lsr[r]);
    }
}

extern "C" void kernel_launch(void* const* d_in, const int* in_sizes, int n_in,
                              void* d_out, int out_size, void* d_ws, size_t ws_size,
                              hipStream_t stream)
{
  const float* x  = (const float*)d_in[0];
  const float* Wq = (const float*)d_in[2];
  const float* bq = (const float*)d_in[3];
  const float* Wk = (const float*)d_in[4];
  const float* bk = (const float*)d_in[5];
  const float* Wv = (const float*)d_in[6];
  const float* bv = (const float*)d_in[7];
  const float* Wo = (const float*)d_in[8];
  const float* bo = (const float*)d_in[9];
  float* out = (float*)d_out;

  char* ws = (char*)d_ws;
  size_t off = 0;
  auto alloc = [&](size_t bytes) { char* p = ws + off; off += bytes; return p; };
  const size_t XN = (size_t)NROWS * DM;   // 4,194,304
  const size_t WN = (size_t)DM * DM;      // 1,048,576

  ushort* Xh  = (ushort*)alloc(XN * 2);
  ushort* Wh  = (ushort*)alloc(3 * WN * 2);   // packed Wq|Wk|Wv
  ushort* Woh = (ushort*)alloc(WN * 2);
  ushort* Qb  = (ushort*)alloc(XN * 2);
  ushort* Kb  = (ushort*)alloc(XN * 2);
  ushort* Vt  = (ushort*)alloc(XN * 2);
  ushort* Ob  = (ushort*)alloc(XN * 2);
  (void)ws_size; (void)in_sizes; (void)n_in; (void)out_size;

  const int total4 = (int)(XN / 4 + 4 * (WN / 4));   // 2,097,152
  tohalf5<<<total4 / 256, 256, 0, stream>>>(x, Wq, Wk, Wv, Wo, Xh, Wh, Woh);

  gemm_half<0, 4, 4><<<dim3(24, 32), 256, 0, stream>>>(
      Xh, Wh, bq, bk, bv, nullptr, Qb, Kb, Vt, 3072);
  attn_kernel<<<2048, 128, 0, stream>>>(Qb, Kb, Vt, Ob);
  gemm_half<1, 2, 4><<<dim3(8, 64), 256, 0, stream>>>(
      Ob, Woh, bo, nullptr, nullptr, out, nullptr, nullptr, nullptr, 1024);
}